// Round 5
// baseline (83.587 us; speedup 1.0000x reference)
//
#include <hip/hip_runtime.h>

// x: (32, 3, 1024, 1024) f32, l: (32,2) i32
// out = [ full: 32*3*1024*1024 f32 , patch: 32*3*128*128 f32 ]
//
// window rows = l0 - 193 + i (i in [0,128)), cols = l1 - 193 + j (j in [0,128))
// patch[b,c,i,j] = valid ? x[b,c,row,col] : 0
// full = x masked to the valid window, 0 elsewhere.

#define FULL_ELEMS  (32L * 3 * 1024 * 1024)   // 100663296
#define FULL_ROWS   98304                     // 32*3*1024

// memset-shaped sweep: each block owns ROWS_PER_BLOCK contiguous rows and
// loops over them; 1 float4 store per thread per row, scalar base increment.
#define ROWS_PER_BLOCK 16
#define SWEEP_BLOCKS   (FULL_ROWS / ROWS_PER_BLOCK)   // 6144
// patch: 393216 float4s, one per thread -> 1536 blocks.
#define PATCH_BLOCKS   1536

__global__ __launch_bounds__(256) void retina_fused(const float* __restrict__ x,
                                                    const int* __restrict__ l,
                                                    float* __restrict__ full,
                                                    float* __restrict__ patch) {
    int bid = blockIdx.x;
    if (bid < SWEEP_BLOCKS) {
        // ---- full: grid-stride over 16 rows, all row control scalar ----
        int w4   = threadIdx.x;              // float4 index within row
        int row0 = bid * ROWS_PER_BLOCK;
        const float4 z = make_float4(0.f, 0.f, 0.f, 0.f);
#pragma unroll 4
        for (int it = 0; it < ROWS_PER_BLOCK; ++it) {
            int row = row0 + it;             // uniform
            int r   = row & 1023;            // row within image (scalar)
            int bc  = row >> 10;             // (b,c) in [0,96)  (scalar)
            int b   = bc / 3;                // scalar magic-mul
            int l0 = l[2 * b];               // s_load, K$ hit
            int l1 = l[2 * b + 1];
            int i  = r - (l0 - 193);         // patch row idx (scalar)
            float4* frow = (float4*)(full + ((long)row << 10));
            if ((unsigned)i >= 128u) {
                frow[w4] = z;                // pure store, memset-like
            } else {
                int jb = (w4 << 2) - (l1 - 193);
                float4 o = z;
                if (jb >= -3 && jb < 128) {  // float4 overlaps col window
                    float4 v = ((const float4*)(x + ((long)row << 10)))[w4];
                    o.x = ((unsigned)(jb + 0) < 128u) ? v.x : 0.f;
                    o.y = ((unsigned)(jb + 1) < 128u) ? v.y : 0.f;
                    o.z = ((unsigned)(jb + 2) < 128u) ? v.z : 0.f;
                    o.w = ((unsigned)(jb + 3) < 128u) ? v.w : 0.f;
                }
                frow[w4] = o;
            }
        }
    } else {
        // ---- patch: one float4 per thread (R0/R2-verified logic) ----
        int tid = (bid - SWEEP_BLOCKS) * 256 + (int)threadIdx.x;
        int j4 = tid & 31;                   // col float4 (128/4)
        int i  = (tid >> 5) & 127;           // patch row
        int bc = tid >> 12;                  // (b,c) in [0,96)
        int b  = bc / 3;
        int l0 = l[2 * b];
        int l1 = l[2 * b + 1];
        int r  = l0 - 193 + i;
        float o[4] = {0.f, 0.f, 0.f, 0.f};
        if ((unsigned)r < 1024u) {
            const float* xrow = x + (((long)bc << 10) + r) * 1024;
            int wbase = l1 - 193 + (j4 << 2);
#pragma unroll
            for (int e = 0; e < 4; ++e) {
                int w = wbase + e;
                if ((unsigned)w < 1024u) o[e] = xrow[w];
            }
        }
        *(float4*)(patch + ((long)tid << 2)) = make_float4(o[0], o[1], o[2], o[3]);
    }
}

extern "C" void kernel_launch(void* const* d_in, const int* in_sizes, int n_in,
                              void* d_out, int out_size, void* d_ws, size_t ws_size,
                              hipStream_t stream) {
    const float* x = (const float*)d_in[0];
    const int*   l = (const int*)d_in[1];
    float* full  = (float*)d_out;
    float* patch = full + FULL_ELEMS;
    retina_fused<<<SWEEP_BLOCKS + PATCH_BLOCKS, 256, 0, stream>>>(x, l, full, patch);
}

// Round 6
// 77.682 us; speedup vs baseline: 1.0760x; 1.0760x over previous
//
#include <hip/hip_runtime.h>

// x: (32, 3, 1024, 1024) f32, l: (32,2) i32
// out = [ full: 32*3*1024*1024 f32 , patch: 32*3*128*128 f32 ]
//
// window rows = l0 - 193 + i (i in [0,128)), cols = l1 - 193 + j (j in [0,128))
// patch[b,c,i,j] = valid ? x[b,c,row,col] : 0
// full = x masked to the valid window, 0 elsewhere.
//
// Strategy: hipMemsetAsync zeroes the ENTIRE output at rocclr-fill speed
// (measured 6.9-7.0 TB/s = 87% of peak on this chip); then one small kernel
// writes only the valid window elements (<= 12.6 MB) into full and patch.

#define FULL_ELEMS  (32L * 3 * 1024 * 1024)   // 100663296
#define PATCH_ELEMS (32L * 3 * 128 * 128)     // 1572864

// window tasks: 96 (b,c) images x 128 patch rows = 12288 row-tasks.
// 2 row-tasks per 256-thread block (128 threads per row, thread j = one col).
#define WIN_BLOCKS 6144

__global__ __launch_bounds__(256) void retina_window(const float* __restrict__ x,
                                                     const int* __restrict__ l,
                                                     float* __restrict__ full,
                                                     float* __restrict__ patch) {
    int task = (blockIdx.x << 1) + (threadIdx.x >> 7);  // bc*128 + i
    int j    = threadIdx.x & 127;        // patch col
    int i    = task & 127;               // patch row
    int bc   = task >> 7;                // (b,c) in [0,96)
    int b    = bc / 3;                   // magic-mul
    int l0 = l[2 * b];
    int l1 = l[2 * b + 1];
    int r  = l0 - 193 + i;               // image row
    if ((unsigned)r >= 1024u) return;    // whole patch row invalid -> stays 0
    int c  = l1 - 193 + j;               // image col
    if ((unsigned)c >= 1024u) return;    // this element invalid -> stays 0
    long xidx = (((long)bc << 10) + r) * 1024 + c;
    float v = x[xidx];
    full[xidx] = v;                                        // coalesced 512B/row
    patch[((long)task << 7) + j] = v;                      // coalesced 512B/row
}

extern "C" void kernel_launch(void* const* d_in, const int* in_sizes, int n_in,
                              void* d_out, int out_size, void* d_ws, size_t ws_size,
                              hipStream_t stream) {
    const float* x = (const float*)d_in[0];
    const int*   l = (const int*)d_in[1];
    float* full  = (float*)d_out;
    float* patch = full + FULL_ELEMS;

    // Zero everything (full + patch) at rocclr-fill speed.
    hipMemsetAsync(d_out, 0, (size_t)out_size * sizeof(float), stream);
    // Write only the valid window elements.
    retina_window<<<WIN_BLOCKS, 256, 0, stream>>>(x, l, full, patch);
}

// Round 8
// 69.092 us; speedup vs baseline: 1.2098x; 1.1243x over previous
//
#include <hip/hip_runtime.h>

// x: (32, 3, 1024, 1024) f32, l: (32,2) i32
// out = [ full: 32*3*1024*1024 f32 , patch: 32*3*128*128 f32 ]
//
// window rows = l0 - 193 + i (i in [0,128)), cols = l1 - 193 + j (j in [0,128))
// patch[b,c,i,j] = valid ? x[b,c,row,col] : 0
// full = x masked to the valid window, 0 elsewhere.
//
// Structure = R2 (best: 70.6 us): 1 block = 1 image row, scalar window control,
// one float4 store per thread. NEW: nontemporal stores (nt flag) so the 409 MB
// streaming store sweep does not write-allocate in L2.
// (nt builtin needs a NATIVE vector type, not HIP_vector_type -> ext_vector_type)

typedef float floatx4 __attribute__((ext_vector_type(4)));

#define FULL_ELEMS  (32L * 3 * 1024 * 1024)   // 100663296

// full: 1 block = 1 image row (1024 floats = 256 float4s, threadIdx.x = w4).
#define FULL_BLOCKS 98304
// patch: 393216 float4s, one per thread -> 1536 blocks.
#define PATCH_BLOCKS 1536

__global__ __launch_bounds__(256) void retina_fused(const float* __restrict__ x,
                                                    const int* __restrict__ l,
                                                    float* __restrict__ full,
                                                    float* __restrict__ patch) {
    int bid = blockIdx.x;
    if (bid < FULL_BLOCKS) {
        // ---- full: one row per block, all control scalar ----
        int r  = bid & 1023;                 // row within image   (scalar)
        int bc = bid >> 10;                  // (b,c) in [0,96)    (scalar)
        int b  = bc / 3;                     // scalar magic-mul
        int l0 = l[2 * b];                   // s_load (K$)
        int l1 = l[2 * b + 1];
        int i  = r - (l0 - 193);             // patch row idx      (scalar)
        floatx4* frow = (floatx4*)(full + ((long)bid << 10));
        int w4 = threadIdx.x;
        floatx4 o = (floatx4)(0.f);
        if ((unsigned)i < 128u) {
            const floatx4* xrow = (const floatx4*)(x + ((long)bid << 10));
            int jb = (w4 << 2) - (l1 - 193); // patch col of elem 0 (per-thread)
            if (jb >= -3 && jb < 128) {      // float4 overlaps col window
                floatx4 v = xrow[w4];
                o.x = ((unsigned)(jb + 0) < 128u) ? v.x : 0.f;
                o.y = ((unsigned)(jb + 1) < 128u) ? v.y : 0.f;
                o.z = ((unsigned)(jb + 2) < 128u) ? v.z : 0.f;
                o.w = ((unsigned)(jb + 3) < 128u) ? v.w : 0.f;
            }
        }
        __builtin_nontemporal_store(o, &frow[w4]);
    } else {
        // ---- patch: one float4 per thread (R0/R2-verified logic) ----
        int tid = (bid - FULL_BLOCKS) * 256 + (int)threadIdx.x;
        int j4 = tid & 31;                   // col float4 (128/4)
        int i  = (tid >> 5) & 127;           // patch row
        int bc = tid >> 12;                  // (b,c) in [0,96)
        int b  = bc / 3;
        int l0 = l[2 * b];
        int l1 = l[2 * b + 1];
        int r  = l0 - 193 + i;
        floatx4 o = (floatx4)(0.f);
        if ((unsigned)r < 1024u) {
            const float* xrow = x + (((long)bc << 10) + r) * 1024;
            int wbase = l1 - 193 + (j4 << 2);
#pragma unroll
            for (int e = 0; e < 4; ++e) {
                int w = wbase + e;
                if ((unsigned)w < 1024u) o[e] = xrow[w];
            }
        }
        __builtin_nontemporal_store(o, (floatx4*)(patch + ((long)tid << 2)));
    }
}

extern "C" void kernel_launch(void* const* d_in, const int* in_sizes, int n_in,
                              void* d_out, int out_size, void* d_ws, size_t ws_size,
                              hipStream_t stream) {
    const float* x = (const float*)d_in[0];
    const int*   l = (const int*)d_in[1];
    float* full  = (float*)d_out;
    float* patch = full + FULL_ELEMS;
    retina_fused<<<FULL_BLOCKS + PATCH_BLOCKS, 256, 0, stream>>>(x, l, full, patch);
}

// Round 9
// 68.442 us; speedup vs baseline: 1.2213x; 1.0095x over previous
//
#include <hip/hip_runtime.h>

// x: (32, 3, 1024, 1024) f32, l: (32,2) i32
// out = [ full: 32*3*1024*1024 f32 , patch: 32*3*128*128 f32 ]
//
// window rows = l0 - 193 + i (i in [0,128)), cols = l1 - 193 + j (j in [0,128))
// patch[b,c,i,j] = valid ? x[b,c,row,col] : 0
// full = x masked to the valid window, 0 elsewhere.
//
// Structure = R7 (best: 69.1 us): 1 block = 1 image row, scalar window control,
// one nt float4 store per thread. NEW: patch blocks FIRST in the grid so the
// gather-heavy tail hides under the big sweep and warms L2 with the x window.

typedef float floatx4 __attribute__((ext_vector_type(4)));

#define FULL_ELEMS  (32L * 3 * 1024 * 1024)   // 100663296

#define FULL_BLOCKS 98304     // 1 block = 1 image row (256 float4s)
#define PATCH_BLOCKS 1536     // 393216 float4s, one per thread

__global__ __launch_bounds__(256) void retina_fused(const float* __restrict__ x,
                                                    const int* __restrict__ l,
                                                    float* __restrict__ full,
                                                    float* __restrict__ patch) {
    int bid = blockIdx.x;
    if (bid >= PATCH_BLOCKS) {
        // ---- full: one row per block, all control scalar ----
        int row = bid - PATCH_BLOCKS;        // image row id in [0, 98304)
        int r  = row & 1023;                 // row within image   (scalar)
        int bc = row >> 10;                  // (b,c) in [0,96)    (scalar)
        int b  = bc / 3;                     // scalar magic-mul
        int l0 = l[2 * b];                   // s_load (K$)
        int l1 = l[2 * b + 1];
        int i  = r - (l0 - 193);             // patch row idx      (scalar)
        floatx4* frow = (floatx4*)(full + ((long)row << 10));
        int w4 = threadIdx.x;
        floatx4 o = (floatx4)(0.f);
        if ((unsigned)i < 128u) {
            const floatx4* xrow = (const floatx4*)(x + ((long)row << 10));
            int jb = (w4 << 2) - (l1 - 193); // patch col of elem 0 (per-thread)
            if (jb >= -3 && jb < 128) {      // float4 overlaps col window
                floatx4 v = xrow[w4];
                o.x = ((unsigned)(jb + 0) < 128u) ? v.x : 0.f;
                o.y = ((unsigned)(jb + 1) < 128u) ? v.y : 0.f;
                o.z = ((unsigned)(jb + 2) < 128u) ? v.z : 0.f;
                o.w = ((unsigned)(jb + 3) < 128u) ? v.w : 0.f;
            }
        }
        __builtin_nontemporal_store(o, &frow[w4]);
    } else {
        // ---- patch: one float4 per thread, runs FIRST (hidden under sweep) ----
        int tid = bid * 256 + (int)threadIdx.x;
        int j4 = tid & 31;                   // col float4 (128/4)
        int i  = (tid >> 5) & 127;           // patch row
        int bc = tid >> 12;                  // (b,c) in [0,96)
        int b  = bc / 3;
        int l0 = l[2 * b];
        int l1 = l[2 * b + 1];
        int r  = l0 - 193 + i;
        floatx4 o = (floatx4)(0.f);
        if ((unsigned)r < 1024u) {
            const float* xrow = x + (((long)bc << 10) + r) * 1024;
            int wbase = l1 - 193 + (j4 << 2);
#pragma unroll
            for (int e = 0; e < 4; ++e) {
                int w = wbase + e;
                if ((unsigned)w < 1024u) o[e] = xrow[w];
            }
        }
        __builtin_nontemporal_store(o, (floatx4*)(patch + ((long)tid << 2)));
    }
}

extern "C" void kernel_launch(void* const* d_in, const int* in_sizes, int n_in,
                              void* d_out, int out_size, void* d_ws, size_t ws_size,
                              hipStream_t stream) {
    const float* x = (const float*)d_in[0];
    const int*   l = (const int*)d_in[1];
    float* full  = (float*)d_out;
    float* patch = full + FULL_ELEMS;
    retina_fused<<<FULL_BLOCKS + PATCH_BLOCKS, 256, 0, stream>>>(x, l, full, patch);
}